// Round 1
// baseline (273.535 us; speedup 1.0000x reference)
//
#include <hip/hip_runtime.h>
#include <stdint.h>

#define N_BOX 128
#define HW    262144          // 512*512
#define SPLIT 16
#define CHUNK (HW / SPLIT)    // 16384 floats per block
#define TOPK  64

// ---------------- Kernel V: per-(mask, split) partial sums ----------------
// grid = N_BOX*SPLIT = 2048 blocks, 256 threads. Each thread: 16 float4 loads.
__global__ __launch_bounds__(256) void k_mask_partial(
    const float* __restrict__ masks, const float* __restrict__ depth,
    float* __restrict__ part) {
  const int b = blockIdx.x;
  const int m = b >> 4;             // / SPLIT
  const int s = b & (SPLIT - 1);
  const float4* mk = reinterpret_cast<const float4*>(masks + (size_t)m * HW + (size_t)s * CHUNK);
  const float4* dp = reinterpret_cast<const float4*>(depth + (size_t)s * CHUNK);
  const int t = threadIdx.x;

  float c = 0.f, s1 = 0.f, s2 = 0.f;
#pragma unroll
  for (int j = 0; j < 16; ++j) {
    const int i = t + j * 256;
    float4 mv = mk[i];
    float4 dv = dp[i];
    if (mv.x > 0.5f && dv.x > 1e-4f) { c += 1.f; s1 += dv.x; s2 += dv.x * dv.x; }
    if (mv.y > 0.5f && dv.y > 1e-4f) { c += 1.f; s1 += dv.y; s2 += dv.y * dv.y; }
    if (mv.z > 0.5f && dv.z > 1e-4f) { c += 1.f; s1 += dv.z; s2 += dv.z * dv.z; }
    if (mv.w > 0.5f && dv.w > 1e-4f) { c += 1.f; s1 += dv.w; s2 += dv.w * dv.w; }
  }
  // wave (64-lane) reduction
  for (int off = 32; off > 0; off >>= 1) {
    c  += __shfl_down(c,  off);
    s1 += __shfl_down(s1, off);
    s2 += __shfl_down(s2, off);
  }
  __shared__ float red[3][4];
  const int wid = t >> 6, lane = t & 63;
  if (lane == 0) { red[0][wid] = c; red[1][wid] = s1; red[2][wid] = s2; }
  __syncthreads();
  if (t == 0) {
    float C  = red[0][0] + red[0][1] + red[0][2] + red[0][3];
    float S1 = red[1][0] + red[1][1] + red[1][2] + red[1][3];
    float S2 = red[2][0] + red[2][1] + red[2][2] + red[2][3];
    part[b * 3 + 0] = C;
    part[b * 3 + 1] = S1;
    part[b * 3 + 2] = S2;
  }
}

// ---------------- Kernel F: finalize per-box scalars ----------------
__device__ __forceinline__ float sigf(float x) { return 1.f / (1.f + expf(-x)); }

__global__ __launch_bounds__(128) void k_finalize(
    const float* __restrict__ boxes, const float* __restrict__ conf,
    const float* __restrict__ part, float* __restrict__ out) {
  const int m = threadIdx.x;
  float C = 0.f, S1 = 0.f, S2 = 0.f;
#pragma unroll
  for (int s = 0; s < SPLIT; ++s) {
    C  += part[(m * SPLIT + s) * 3 + 0];
    S1 += part[(m * SPLIT + s) * 3 + 1];
    S2 += part[(m * SPLIT + s) * 3 + 2];
  }
  const float cntf = fmaxf(C, 1.f);
  const float mean = S1 / cntf;
  float var = S2 / cntf - mean * mean;
  var = (C > 0.f) ? fmaxf(var, 0.f) : 0.f;

  const float x1 = boxes[m * 4 + 0], y1 = boxes[m * 4 + 1];
  const float x2 = boxes[m * 4 + 2], y2 = boxes[m * 4 + 3];
  const float bw = fmaxf(x2 - x1, 0.f);
  const float bh = fmaxf(y2 - y1, 0.f);
  const float area = fminf(fmaxf(bw * bh, 0.f), 1.f);
  const float cf = conf[m];
  const float tall = fminf(fmaxf(bh / (bw + 1e-6f), 0.f), 10.f);
  const float thin = sigf((tall - 1.2f) * 2.f);
  const float unst = fminf(fmaxf(0.35f * thin + 0.35f * sigf(var * 6.f) + 0.3f * (1.f - cf), 0.f), 1.f);
  const float slip = fminf(fmaxf(0.45f * sigf(var * 8.f) + 0.25f * (1.f - cf) + 0.3f * sigf((area - 0.05f) * 3.f), 0.f), 1.f);
  const float sup  = fminf(fmaxf(1.f - unst, 0.f), 1.f);
  out[m]           = unst;
  out[N_BOX + m]   = slip;
  out[2 * N_BOX + m] = sup;
}

// ---------------- Kernel T: IoU + exact top-64 ----------------
// Single block, 1024 threads. Keys held in registers (16 u64/thread).
// key = (monotonic_u32(masked_value) << 32) | (0xFFFFFFFF - flat_idx)
// => descending u64 order == (value desc, flat index asc) == jax.lax.top_k order.
__global__ __launch_bounds__(1024) void k_topk(
    const float* __restrict__ boxes, float* __restrict__ out) {
  __shared__ float X1[N_BOX], Y1[N_BOX], X2[N_BOX], Y2[N_BOX], A[N_BOX];
  __shared__ unsigned hist[256];
  __shared__ uint64_t sh_prefix;
  __shared__ unsigned sh_k;
  __shared__ unsigned gcnt;
  __shared__ unsigned long long cand[TOPK];

  const int t = threadIdx.x;
  if (t < N_BOX) {
    const float x1 = boxes[t * 4 + 0], y1 = boxes[t * 4 + 1];
    const float x2 = boxes[t * 4 + 2], y2 = boxes[t * 4 + 3];
    X1[t] = x1; Y1[t] = y1; X2[t] = x2; Y2[t] = y2;
    A[t] = fmaxf(x2 - x1, 0.f) * fmaxf(y2 - y1, 0.f);
  }
  if (t == 0) { sh_prefix = 0ULL; sh_k = TOPK; gcnt = 0; }
  __syncthreads();

  uint64_t key[16];
#pragma unroll
  for (int j = 0; j < 16; ++j) {
    const int e = t + j * 1024;
    const int i = e >> 7, jj = e & 127;
    const float xx1 = fmaxf(X1[i], X1[jj]);
    const float yy1 = fmaxf(Y1[i], Y1[jj]);
    const float xx2 = fminf(X2[i], X2[jj]);
    const float yy2 = fminf(Y2[i], Y2[jj]);
    const float inter = fmaxf(xx2 - xx1, 0.f) * fmaxf(yy2 - yy1, 0.f);
    const float uni = A[i] + A[jj] - inter;
    float iou = inter / (uni + 1e-6f);
    if (i == jj) iou = 0.f;                   // diagonal zeroed (== * (1-eye))
    const float mval = (iou > 0.02f) ? iou : -1.0f;
    uint32_t u = __float_as_uint(mval);
    u = (u & 0x80000000u) ? ~u : (u | 0x80000000u);   // monotonic float->u32
    key[j] = ((uint64_t)u << 32) | (uint64_t)(0xFFFFFFFFu - (uint32_t)e);
  }

  // 8-pass byte radix-select: exact 64th-largest key (all keys distinct).
  uint64_t prefix = 0ULL;
  unsigned k = TOPK;
  for (int p = 7; p >= 0; --p) {
    if (t < 256) hist[t] = 0;
    __syncthreads();
    const uint64_t hi_mask = (p == 7) ? 0ULL : ~((1ULL << ((p + 1) * 8)) - 1ULL);
#pragma unroll
    for (int j = 0; j < 16; ++j) {
      if ((key[j] & hi_mask) == prefix)
        atomicAdd(&hist[(unsigned)((key[j] >> (p * 8)) & 255ULL)], 1u);
    }
    __syncthreads();
    if (t == 0) {
      unsigned c = 0; int sel = 255;
      for (int bb = 255; bb >= 0; --bb) {
        const unsigned h = hist[bb];
        if (c + h >= k) { sel = bb; sh_k = k - c; break; }
        c += h;
      }
      sh_prefix = prefix | ((uint64_t)sel << (p * 8));
    }
    __syncthreads();
    prefix = sh_prefix;
    k = sh_k;
  }
  // prefix == exact 64th-largest key; gather the 64 keys >= prefix.
#pragma unroll
  for (int j = 0; j < 16; ++j) {
    if (key[j] >= prefix) {
      const unsigned pos = atomicAdd(&gcnt, 1u);
      if (pos < TOPK) cand[pos] = (unsigned long long)key[j];
    }
  }
  __syncthreads();

  // Wave 0: bitonic sort 64 keys descending, then emit outputs.
  if (t < 64) {
    unsigned long long v = cand[t];
    for (int size = 2; size <= 64; size <<= 1) {
      for (int stride = size >> 1; stride > 0; stride >>= 1) {
        const unsigned long long other = __shfl_xor(v, stride);
        const bool blk   = ((t & size) == 0);     // descending block
        const bool lower = ((t & stride) == 0);
        const unsigned long long mx = (v > other) ? v : other;
        const unsigned long long mn = (v > other) ? other : v;
        v = (blk == lower) ? mx : mn;
      }
    }
    const uint32_t mh = (uint32_t)(v >> 32);
    const uint32_t u  = (mh & 0x80000000u) ? (mh ^ 0x80000000u) : ~mh;
    const float val   = __uint_as_float(u);
    const uint32_t e  = 0xFFFFFFFFu - (uint32_t)(v & 0xFFFFFFFFu);
    const bool valid  = (val > 0.02f);
    const float pi = valid ? (float)(e >> 7)  : 0.f;
    const float pj = valid ? (float)(e & 127) : 0.f;
    const float coll = valid ? fminf(fmaxf(val * 5.f, 0.f), 1.f) : 0.f;
    out[3 * N_BOX + 2 * t + 0] = pi;
    out[3 * N_BOX + 2 * t + 1] = pj;
    out[3 * N_BOX + 2 * TOPK + t] = coll;   // 384 + 128 = 512
  }
}

extern "C" void kernel_launch(void* const* d_in, const int* in_sizes, int n_in,
                              void* d_out, int out_size, void* d_ws, size_t ws_size,
                              hipStream_t stream) {
  const float* boxes = (const float*)d_in[0];
  const float* masks = (const float*)d_in[1];
  const float* conf  = (const float*)d_in[2];
  const float* depth = (const float*)d_in[3];
  float* out  = (float*)d_out;
  float* part = (float*)d_ws;   // N_BOX*SPLIT*3 floats = 24 KB, fully written each call

  hipLaunchKernelGGL(k_mask_partial, dim3(N_BOX * SPLIT), dim3(256), 0, stream,
                     masks, depth, part);
  hipLaunchKernelGGL(k_topk, dim3(1), dim3(1024), 0, stream, boxes, out);
  hipLaunchKernelGGL(k_finalize, dim3(1), dim3(128), 0, stream,
                     boxes, conf, part, out);
}

// Round 2
// 218.333 us; speedup vs baseline: 1.2528x; 1.2528x over previous
//
#include <hip/hip_runtime.h>
#include <stdint.h>

#define N_BOX 128
#define HW    262144          // 512*512
#define SPLIT 16
#define CHUNK (HW / SPLIT)    // 16384 floats per block
#define TOPK  64
typedef unsigned long long u64;

// ---------------- Kernel V: per-(mask, split) partial sums ----------------
__global__ __launch_bounds__(256) void k_mask_partial(
    const float* __restrict__ masks, const float* __restrict__ depth,
    float* __restrict__ part) {
  const int b = blockIdx.x;
  const int m = b >> 4;             // / SPLIT
  const int s = b & (SPLIT - 1);
  const float4* mk = reinterpret_cast<const float4*>(masks + (size_t)m * HW + (size_t)s * CHUNK);
  const float4* dp = reinterpret_cast<const float4*>(depth + (size_t)s * CHUNK);
  const int t = threadIdx.x;

  float c = 0.f, s1 = 0.f, s2 = 0.f;
#pragma unroll
  for (int j = 0; j < 16; ++j) {
    const int i = t + j * 256;
    float4 mv = mk[i];
    float4 dv = dp[i];
    if (mv.x > 0.5f && dv.x > 1e-4f) { c += 1.f; s1 += dv.x; s2 += dv.x * dv.x; }
    if (mv.y > 0.5f && dv.y > 1e-4f) { c += 1.f; s1 += dv.y; s2 += dv.y * dv.y; }
    if (mv.z > 0.5f && dv.z > 1e-4f) { c += 1.f; s1 += dv.z; s2 += dv.z * dv.z; }
    if (mv.w > 0.5f && dv.w > 1e-4f) { c += 1.f; s1 += dv.w; s2 += dv.w * dv.w; }
  }
  for (int off = 32; off > 0; off >>= 1) {
    c  += __shfl_down(c,  off);
    s1 += __shfl_down(s1, off);
    s2 += __shfl_down(s2, off);
  }
  __shared__ float red[3][4];
  const int wid = t >> 6, lane = t & 63;
  if (lane == 0) { red[0][wid] = c; red[1][wid] = s1; red[2][wid] = s2; }
  __syncthreads();
  if (t == 0) {
    part[b * 3 + 0] = red[0][0] + red[0][1] + red[0][2] + red[0][3];
    part[b * 3 + 1] = red[1][0] + red[1][1] + red[1][2] + red[1][3];
    part[b * 3 + 2] = red[2][0] + red[2][1] + red[2][2] + red[2][3];
  }
}

// ---------------- bitonic helpers (64-lane wave, u64 keys, descending) ----
__device__ __forceinline__ u64 sort64_desc(u64 v, int lane) {
#pragma unroll
  for (int size = 2; size <= 64; size <<= 1) {
#pragma unroll
    for (int stride = size >> 1; stride > 0; stride >>= 1) {
      const u64 o = __shfl_xor(v, stride);
      const bool blk   = ((lane & size) == 0);
      const bool lower = ((lane & stride) == 0);
      const u64 mx = (v > o) ? v : o;
      const u64 mn = (v > o) ? o : v;
      v = (blk == lower) ? mx : mn;
    }
  }
  return v;
}

// v: sorted desc (this wave's running top). s: another sorted-desc list.
// Returns top-64 of the union, sorted desc. Exact for distinct keys.
__device__ __forceinline__ u64 merge64_desc(u64 v, u64 s, int lane) {
  const u64 r = __shfl_xor(s, 63);        // reversed -> ascending
  v = (v > r) ? v : r;                    // elementwise max -> bitonic
#pragma unroll
  for (int stride = 32; stride > 0; stride >>= 1) {
    const u64 o = __shfl_xor(v, stride);
    const bool lower = ((lane & stride) == 0);
    const u64 mx = (v > o) ? v : o;
    const u64 mn = (v > o) ? o : v;
    v = lower ? mx : mn;                  // descending merge
  }
  return v;
}

__device__ __forceinline__ float sigf(float x) { return 1.f / (1.f + expf(-x)); }

// ---------------- Kernel T: IoU + exact top-64 + fused finalize ----------
// 1024 threads = 16 waves. Wave w streams elements [w*1024, (w+1)*1024) in
// 16 batches of 64, maintaining a register-resident sorted top-64.
// key = (monotonic_u32(masked_value) << 32) | (0xFFFFFFFF - flat_idx):
// descending u64 order == (value desc, index asc) == jax.lax.top_k order.
__global__ __launch_bounds__(1024) void k_topk_fin(
    const float* __restrict__ boxes, const float* __restrict__ conf,
    const float* __restrict__ part, float* __restrict__ out) {
  __shared__ float X1[N_BOX], Y1[N_BOX], X2[N_BOX], Y2[N_BOX], A[N_BOX];
  __shared__ u64 wtop[16][TOPK];

  const int t = threadIdx.x;
  const int lane = t & 63;
  const int w = t >> 6;

  if (t < N_BOX) {
    const float x1 = boxes[t * 4 + 0], y1 = boxes[t * 4 + 1];
    const float x2 = boxes[t * 4 + 2], y2 = boxes[t * 4 + 3];
    X1[t] = x1; Y1[t] = y1; X2[t] = x2; Y2[t] = y2;
    A[t] = fmaxf(x2 - x1, 0.f) * fmaxf(y2 - y1, 0.f);
  }
  __syncthreads();

  u64 v = 0ULL;
#pragma unroll
  for (int b = 0; b < 16; ++b) {
    const int e = w * 1024 + b * 64 + lane;
    const int i = e >> 7, jj = e & 127;
    const float xx1 = fmaxf(X1[i], X1[jj]);
    const float yy1 = fmaxf(Y1[i], Y1[jj]);
    const float xx2 = fminf(X2[i], X2[jj]);
    const float yy2 = fminf(Y2[i], Y2[jj]);
    const float inter = fmaxf(xx2 - xx1, 0.f) * fmaxf(yy2 - yy1, 0.f);
    const float uni = A[i] + A[jj] - inter;
    float iou = inter / (uni + 1e-6f);
    if (i == jj) iou = 0.f;
    const float mval = (iou > 0.02f) ? iou : -1.0f;
    uint32_t u = __float_as_uint(mval);
    u = (u & 0x80000000u) ? ~u : (u | 0x80000000u);   // monotonic float->u32
    const u64 key = ((u64)u << 32) | (u64)(0xFFFFFFFFu - (uint32_t)e);

    if (b == 0) {
      v = sort64_desc(key, lane);
    } else {
      const u64 cut = __shfl(v, 63);      // current 64th-largest
      if (__any(key > cut)) {             // batch can contribute?
        const u64 s = sort64_desc(key, lane);
        v = merge64_desc(v, s, lane);
      }
    }
  }
  wtop[w][lane] = v;
  __syncthreads();

  if (w == 0) {
    // merge the 16 per-wave sorted lists
#pragma unroll
    for (int ww = 1; ww < 16; ++ww)
      v = merge64_desc(v, wtop[ww][lane], lane);
    // emit pairs + collision (lane t -> slot t)
    const uint32_t mh = (uint32_t)(v >> 32);
    const uint32_t u  = (mh & 0x80000000u) ? (mh ^ 0x80000000u) : ~mh;
    const float val   = __uint_as_float(u);
    const uint32_t e  = 0xFFFFFFFFu - (uint32_t)(v & 0xFFFFFFFFu);
    const bool valid  = (val > 0.02f);
    out[3 * N_BOX + 2 * lane + 0] = valid ? (float)(e >> 7)  : 0.f;
    out[3 * N_BOX + 2 * lane + 1] = valid ? (float)(e & 127) : 0.f;
    out[3 * N_BOX + 2 * TOPK + lane] = valid ? fminf(fmaxf(val * 5.f, 0.f), 1.f) : 0.f;
  } else if (w == 2 || w == 3) {
    // fused finalize: per-box scalars (concurrent with wave 0's merge)
    const int m = t - 128;
    float C = 0.f, S1 = 0.f, S2 = 0.f;
#pragma unroll
    for (int s = 0; s < SPLIT; ++s) {
      C  += part[(m * SPLIT + s) * 3 + 0];
      S1 += part[(m * SPLIT + s) * 3 + 1];
      S2 += part[(m * SPLIT + s) * 3 + 2];
    }
    const float cntf = fmaxf(C, 1.f);
    const float mean = S1 / cntf;
    float var = S2 / cntf - mean * mean;
    var = (C > 0.f) ? fmaxf(var, 0.f) : 0.f;

    const float x1 = X1[m], y1 = Y1[m], x2 = X2[m], y2 = Y2[m];
    const float bw = fmaxf(x2 - x1, 0.f);
    const float bh = fmaxf(y2 - y1, 0.f);
    const float area = fminf(fmaxf(bw * bh, 0.f), 1.f);
    const float cf = conf[m];
    const float tall = fminf(fmaxf(bh / (bw + 1e-6f), 0.f), 10.f);
    const float thin = sigf((tall - 1.2f) * 2.f);
    const float unst = fminf(fmaxf(0.35f * thin + 0.35f * sigf(var * 6.f) + 0.3f * (1.f - cf), 0.f), 1.f);
    const float slip = fminf(fmaxf(0.45f * sigf(var * 8.f) + 0.25f * (1.f - cf) + 0.3f * sigf((area - 0.05f) * 3.f), 0.f), 1.f);
    out[m]             = unst;
    out[N_BOX + m]     = slip;
    out[2 * N_BOX + m] = fminf(fmaxf(1.f - unst, 0.f), 1.f);
  }
}

extern "C" void kernel_launch(void* const* d_in, const int* in_sizes, int n_in,
                              void* d_out, int out_size, void* d_ws, size_t ws_size,
                              hipStream_t stream) {
  const float* boxes = (const float*)d_in[0];
  const float* masks = (const float*)d_in[1];
  const float* conf  = (const float*)d_in[2];
  const float* depth = (const float*)d_in[3];
  float* out  = (float*)d_out;
  float* part = (float*)d_ws;   // N_BOX*SPLIT*3 floats = 24 KB, fully written each call

  hipLaunchKernelGGL(k_mask_partial, dim3(N_BOX * SPLIT), dim3(256), 0, stream,
                     masks, depth, part);
  hipLaunchKernelGGL(k_topk_fin, dim3(1), dim3(1024), 0, stream,
                     boxes, conf, part, out);
}